// Round 8
// baseline (12543.608 us; speedup 1.0000x reference)
//
#include <hip/hip_runtime.h>

#define NP   19
#define EPB  16
#define BLK  256
#define TMPW 88        // s_tmp row stride: 88%32=24 -> uniform 2-way bank aliasing (free)
#define RSTRIDE 4864   // P_TOTAL columns in R

namespace {
constexpr int P_IO[NP]  = {0,0,0, 1,1,1,1,1,1,1, 2,2,2,2, 2,2,2,2,2};
constexpr int P_II[NP]  = {0,1,2, 0,1,1,1,2,2,2, 0,1,1,1, 2,2,2,2,2};
constexpr int P_LF[NP]  = {0,1,2, 1,0,1,2,1,2,3, 2,1,2,3, 0,1,2,3,4};
constexpr int P_CGB[NP] = {0,1,10, 35,44,53,80,125,170,245, 350,375,420,495, 600,625,700,825,1000};
constexpr float NORMLF[5] = {1.0f, 0.57735026918962576f, 0.44721359549995794f,
                             0.37796447300922722f, 0.33333333333333333f};
}

// ---------------- Phase A per-path body: wave-autonomous, zero barriers ----------------
template<int P>
__device__ __forceinline__ void process_path(
    const int l, const int eloc,
    const float fA, const float (&fB)[3], const float (&fC)[5],
    const float (&rr)[10], const float (&y)[25], float (&acc)[9],
    const float* __restrict__ R, const float* __restrict__ cg,
    float* __restrict__ s_tmp)
{
    constexpr int io = P_IO[P], ii = P_II[P], lf = P_LF[P];
    constexpr int dO = 2*io+1, dI = 2*ii+1, dF = 2*lf+1;
    constexpr int nOI = dO*dI, yb = lf*lf;
    constexpr float nrm = NORMLF[lf];

    // --- W row for OWN edge, 16 columns, straight from global R (L1-hot, 10KB/path).
    //     radii are already per-thread registers: no LDS anywhere in W-gen. ---
    float W[16];
#pragma unroll
    for (int v = 0; v < 16; ++v) W[v] = 0.f;
    const float* Rp = R + P*256 + 16*l;
#pragma unroll
    for (int r = 0; r < 10; ++r) {
        const float4* q = reinterpret_cast<const float4*>(Rp + r*RSTRIDE);
        const float4 q0 = q[0], q1 = q[1], q2 = q[2], q3 = q[3];
        const float rv = rr[r];
        W[0]  += rv*q0.x; W[1]  += rv*q0.y; W[2]  += rv*q0.z; W[3]  += rv*q0.w;
        W[4]  += rv*q1.x; W[5]  += rv*q1.y; W[6]  += rv*q1.z; W[7]  += rv*q1.w;
        W[8]  += rv*q2.x; W[9]  += rv*q2.y; W[10] += rv*q2.z; W[11] += rv*q2.w;
        W[12] += rv*q3.x; W[13] += rv*q3.y; W[14] += rv*q3.z; W[15] += rv*q3.w;
    }

    // --- cgY in registers; cg read from GLOBAL with uniform constexpr indices
    //     (scalar-cache / L1 path — keeps the LDS pipe free) ---
    float cgy[nOI];
#pragma unroll
    for (int j = 0; j < nOI; ++j) {
        float s = 0.f;
#pragma unroll
        for (int f = 0; f < dF; ++f)
            s += cg[P_CGB[P] + j*dF + f] * y[yb + f];
        cgy[j] = s * nrm;
    }

    // --- tmp[v,o] = sum_i F[v,i] * cgY[o,i]   (lane = v); intra-wave exchange ---
#pragma unroll
    for (int o = 0; o < dO; ++o) {
        float t = 0.f;
#pragma unroll
        for (int i = 0; i < dI; ++i) {
            float fv;
            if constexpr (ii == 0)      fv = fA;
            else if constexpr (ii == 1) fv = fB[i];
            else                        fv = fC[i];
            t += fv * cgy[o*dI + i];
        }
        s_tmp[eloc*TMPW + o*16 + l] = t;
    }

    // The 16 writer lanes of this eloc are in the SAME wave64; DS ops execute in
    // issue order per wave. Only compiler reordering must be fenced (0 instructions).
    __asm__ volatile("" ::: "memory");

    // --- out[w,o] += sum_v W[w,v] * tmp[v,o]   (lane = w; b128 broadcast reads) ---
#pragma unroll
    for (int o = 0; o < dO; ++o) {
        const float4* tq = reinterpret_cast<const float4*>(&s_tmp[eloc*TMPW + o*16]);
        const float4 t0 = tq[0], t1 = tq[1], t2 = tq[2], t3 = tq[3];
        float s = W[0]*t0.x  + W[1]*t0.y  + W[2]*t0.z  + W[3]*t0.w
                + W[4]*t1.x  + W[5]*t1.y  + W[6]*t1.z  + W[7]*t1.w
                + W[8]*t2.x  + W[9]*t2.y  + W[10]*t2.z + W[11]*t2.w
                + W[12]*t3.x + W[13]*t3.y + W[14]*t3.z + W[15]*t3.w;
        acc[io*io + o] += s;
    }

    // WAR fence: next path re-writes the same s_tmp addresses; keep reads before that.
    __asm__ volatile("" ::: "memory");
}

template<int P>
__device__ __forceinline__ void process_all(
    const int l, const int eloc,
    const float fA, const float (&fB)[3], const float (&fC)[5],
    const float (&rr)[10], const float (&y)[25], float (&acc)[9],
    const float* __restrict__ R, const float* __restrict__ cg,
    float* __restrict__ s_tmp)
{
    if constexpr (P < NP) {
        process_path<P>(l, eloc, fA, fB, fC, rr, y, acc, R, cg, s_tmp);
        process_all<P+1>(l, eloc, fA, fB, fC, rr, y, acc, R, cg, s_tmp);
    }
}

// ---------------- Phase A: edge-major message materialization ----------------
__global__ __launch_bounds__(BLK, 3)
void se3_msg(const float* __restrict__ F, const float* __restrict__ R,
             const float* __restrict__ Ys, const float* __restrict__ Rad,
             const float* __restrict__ cg,
             const int* __restrict__ Mb,
             float* __restrict__ msg, const int nE)
{
    __shared__ float s_tmp[EPB * TMPW];   // only LDS left: intra-wave v<->w exchange

    const int tid  = threadIdx.x;
    const int l    = tid & 15;
    const int eloc = tid >> 4;
    const int e    = blockIdx.x * EPB + eloc;
    const bool act = (e < nE);
    const int  es  = act ? e : 0;

    const int b = Mb[es];
    const float* Fb = F + (size_t)b * 144;
    const float fA = Fb[l];
    float fB[3], fC[5];
#pragma unroll
    for (int i = 0; i < 3; ++i) fB[i] = Fb[16 + l*3 + i];
#pragma unroll
    for (int i = 0; i < 5; ++i) fC[i] = Fb[64 + l*5 + i];

    float rr[10];
    const float* rp = Rad + (size_t)es * 10;
#pragma unroll
    for (int r = 0; r < 10; ++r) rr[r] = act ? rp[r] : 0.f;   // inactive -> W = 0

    float y[25];
    const float* yr = Ys + (size_t)es * 25;
#pragma unroll
    for (int k = 0; k < 25; ++k) y[k] = yr[k];

    float acc[9];
#pragma unroll
    for (int k = 0; k < 9; ++k) acc[k] = 0.f;

    process_all<0>(l, eloc, fA, fB, fC, rr, y, acc, R, cg, s_tmp);

    // tail: plain coalesced stores, transposed [j][16] layout — no LDS, no atomics
    if (act) {
        float* m = msg + (size_t)e * 144 + l;
#pragma unroll
        for (int j = 0; j < 9; ++j) m[j * 16] = acc[j];
    }
}

// ---------------- Phase B: node gather-reduce (no atomics) ----------------
__global__ __launch_bounds__(BLK)
void se3_gather(const float* __restrict__ msg, const int* __restrict__ off,
                const int* __restrict__ eidx, const float* __restrict__ Nn,
                float* __restrict__ Out, const int nN)
{
    const int l = threadIdx.x & 15;
    const int g = threadIdx.x >> 4;
    const int n = blockIdx.x * 16 + g;
    if (n >= nN) return;

    const int i0 = off[n], i1 = off[n + 1];
    float s[9];
#pragma unroll
    for (int j = 0; j < 9; ++j) s[j] = 0.f;

    for (int idx = i0; idx < i1; ++idx) {
        const int eid = eidx[idx];
        const float* m = msg + (size_t)eid * 144 + l;
#pragma unroll
        for (int j = 0; j < 9; ++j) s[j] += m[j * 16];
    }

    const float nn = Nn[n];
    float* orow = Out + (size_t)n * 144;
    orow[l] = s[0] * nn;
#pragma unroll
    for (int o = 0; o < 3; ++o) orow[16 + l*3 + o] = s[1+o] * nn;
#pragma unroll
    for (int o = 0; o < 5; ++o) orow[64 + l*5 + o] = s[4+o] * nn;
}

// ---------------- CSR build (by destination) ----------------
__global__ void k_count(const int* __restrict__ Ma, int* __restrict__ cur, int E) {
    int e = blockIdx.x * blockDim.x + threadIdx.x;
    if (e < E) atomicAdd(&cur[Ma[e]], 1);
}

__global__ void k_scan(int* __restrict__ cur, int* __restrict__ off, int N) {
    __shared__ int part[BLK];
    const int t = threadIdx.x;
    const int K = (N + BLK - 1) / BLK;
    const int i0 = t * K, i1 = min(i0 + K, N);
    int s = 0;
    for (int i = i0; i < i1; ++i) s += cur[i];
    part[t] = s;
    __syncthreads();
    if (t == 0) {
        int a = 0;
        for (int j = 0; j < BLK; ++j) { int v = part[j]; part[j] = a; a += v; }
        off[N] = a;
    }
    __syncthreads();
    int a = part[t];
    for (int i = i0; i < i1; ++i) {
        int v = cur[i];
        off[i] = a;
        cur[i] = a;       // reuse as scatter cursor
        a += v;
    }
}

__global__ void k_scatter(const int* __restrict__ Ma, int* __restrict__ cur,
                          int* __restrict__ eidx, int E) {
    int e = blockIdx.x * blockDim.x + threadIdx.x;
    if (e < E) {
        int pos = atomicAdd(&cur[Ma[e]], 1);
        eidx[pos] = e;
    }
}

extern "C" void kernel_launch(void* const* d_in, const int* in_sizes, int n_in,
                              void* d_out, int out_size, void* d_ws, size_t ws_size,
                              hipStream_t stream) {
    const float* F   = (const float*)d_in[0];
    const float* R   = (const float*)d_in[1];
    const float* Ys  = (const float*)d_in[2];
    const float* Rad = (const float*)d_in[3];
    const float* cg  = (const float*)d_in[4];
    const float* Nn  = (const float*)d_in[5];
    const int*   Ma  = (const int*)d_in[6];
    const int*   Mb  = (const int*)d_in[7];
    float* Out = (float*)d_out;

    const int nE = in_sizes[6];   // edges
    const int nN = in_sizes[5];   // nodes

    // ws layout: [cur nN][off nN+1][eidx nE][pad][msg nE*144 floats]
    int* wsI  = (int*)d_ws;
    int* cur  = wsI;
    int* off  = wsI + nN;
    int* eidx = wsI + 2*nN + 1;
    size_t msgOff = ((size_t)(2*nN + 1 + nE) + 63) & ~(size_t)63;
    float* msg = (float*)d_ws + msgOff;

    hipMemsetAsync(cur, 0, (size_t)nN * sizeof(int), stream);
    k_count  <<<(nE + BLK - 1) / BLK, BLK, 0, stream>>>(Ma, cur, nE);
    k_scan   <<<1, BLK, 0, stream>>>(cur, off, nN);
    k_scatter<<<(nE + BLK - 1) / BLK, BLK, 0, stream>>>(Ma, cur, eidx, nE);

    se3_msg   <<<(nE + EPB - 1) / EPB, BLK, 0, stream>>>(F, R, Ys, Rad, cg, Mb, msg, nE);
    se3_gather<<<(nN + 15) / 16, BLK, 0, stream>>>(msg, off, eidx, Nn, Out, nN);
}

// Round 9
// 1573.933 us; speedup vs baseline: 7.9696x; 7.9696x over previous
//
#include <hip/hip_runtime.h>

#define NP   19
#define EPB  16
#define BLK  256
#define WST  260        // s_W row stride (words)
#define RSTRIDE 4864    // P_TOTAL columns in R

// ---- per-path metadata (device .rodata; p is wave-uniform -> scalar loads) ----
__device__ const int   d_io[NP]  = {0,0,0, 1,1,1,1,1,1,1, 2,2,2,2, 2,2,2,2,2};
__device__ const int   d_ii[NP]  = {0,1,2, 0,1,1,1,2,2,2, 0,1,1,1, 2,2,2,2,2};
__device__ const int   d_lf[NP]  = {0,1,2, 1,0,1,2,1,2,3, 2,1,2,3, 0,1,2,3,4};
__device__ const int   d_cgb[NP] = {0,1,10, 35,44,53,80,125,170,245, 350,375,420,495, 600,625,700,825,1000};
__device__ const float d_nrm[5]  = {1.0f, 0.57735026918962576f, 0.44721359549995794f,
                                    0.37796447300922722f, 0.33333333333333333f};
__device__ const int   d_fo[3]   = {0, 1, 4};   // F-slice offset per ii (1,3,5 comps)
__device__ const int   d_ob[3]   = {0, 1, 4};   // msg 9-slot base per io

// ---------------- Phase A: edge-major, small-code path loop ----------------
__global__ __launch_bounds__(BLK, 3)
void se3_msg(const float* __restrict__ F, const float* __restrict__ R,
             const float* __restrict__ Ys, const float* __restrict__ Rad,
             const float* __restrict__ cg,
             const int* __restrict__ Mb,
             float* __restrict__ msg, const int nE)
{
    __shared__ float s_cg [1225];          // CG coefficients (4.9 KB, read-broadcast)
    __shared__ float s_rad[EPB][12];       // radii, row padded to 48B for float4 reads
    __shared__ float s_y  [EPB][26];       // Ys row per edge
    __shared__ float s_Fv [EPB*16*9];      // gathered F slices: [eloc][lane v][9]
    __shared__ float s_cgy[EPB][28];       // cgY exchange
    __shared__ float s_tmp[EPB*84];        // tmp exchange  [eloc][o*16+v]
    __shared__ float s_W  [EPB*WST];       // coop W tile   [eloc][w*16+v]
    __shared__ float s_msg[EPB*144];       // message accumulator [eloc][j*16+w]

    const int tid  = threadIdx.x;
    const int l    = tid & 15;
    const int eloc = tid >> 4;
    const int e    = blockIdx.x * EPB + eloc;
    const bool act = (e < nE);
    const int  es  = act ? e : 0;

    // ---- setup staging (once per block) ----
    for (int t = tid; t < 1225; t += BLK) s_cg[t] = cg[t];

    if (l < 10) s_rad[eloc][l] = act ? Rad[(size_t)es*10 + l] : 0.f;  // inactive -> W=0
    if (l >= 10) s_rad[eloc][l & 11] = s_rad[eloc][l & 11];           // keep lanes converged (no-op)
    if (l < 12 && l >= 10) s_rad[eloc][l] = 0.f;                      // pad lanes

    for (int k = l; k < 25; k += 16) s_y[eloc][k] = Ys[(size_t)es*25 + k];

    {
        const int b = Mb[es];
        const float* Fb = F + (size_t)b * 144;
        float* fv = &s_Fv[(eloc*16 + l) * 9];
        fv[0] = Fb[l];
        #pragma unroll
        for (int i = 0; i < 3; ++i) fv[1 + i] = Fb[16 + l*3 + i];
        #pragma unroll
        for (int i = 0; i < 5; ++i) fv[4 + i] = Fb[64 + l*5 + i];
    }
    #pragma unroll
    for (int j = 0; j < 9; ++j) s_msg[eloc*144 + j*16 + l] = 0.f;

    __syncthreads();

    // ---- THE path loop: small body, executed 19x from I$ ----
    #pragma unroll 1
    for (int p = 0; p < NP; ++p) {
        const int io = d_io[p], ii = d_ii[p], lf = d_lf[p];
        const int dO = 2*io + 1, dI = 2*ii + 1, dF = 2*lf + 1;
        const int nOI = dO * dI;
        const int yb  = lf * lf;
        const int cgb = d_cgb[p];
        const int fo  = d_fo[ii];
        const int ob  = d_ob[io];
        const float nrm = d_nrm[lf];

        // stage 1a: coop W. thread owns column c=tid; coalesced R loads.
        {
            float rcol[10];
            const float* Rp = R + p*256 + tid;
            #pragma unroll
            for (int r = 0; r < 10; ++r) rcol[r] = Rp[r * RSTRIDE];
            #pragma unroll 4
            for (int ee = 0; ee < EPB; ++ee) {
                const float4* rp4 = reinterpret_cast<const float4*>(&s_rad[ee][0]);
                const float4 a = rp4[0], bq = rp4[1];
                const float2 cq = *reinterpret_cast<const float2*>(&s_rad[ee][8]);
                float s = a.x*rcol[0] + a.y*rcol[1] + a.z*rcol[2] + a.w*rcol[3]
                        + bq.x*rcol[4] + bq.y*rcol[5] + bq.z*rcol[6] + bq.w*rcol[7]
                        + cq.x*rcol[8] + cq.y*rcol[9];
                s_W[ee*WST + tid] = s;
            }
        }

        // stage 1b: cgY[o,i] = nrm * sum_f cg[o,i,f] * y[yb+f]  (16 lanes cover nOI)
        for (int j0 = 0; j0 < nOI; j0 += 16) {
            const int j = j0 + l;
            if (j < nOI) {
                float s = 0.f;
                const float* cgp = &s_cg[cgb + j*dF];
                const float* yp  = &s_y[eloc][yb];
                for (int f = 0; f < dF; ++f) s += cgp[f] * yp[f];
                s_cgy[eloc][j] = s * nrm;
            }
        }
        __syncthreads();

        // stage 2: tmp[v,o] = sum_i F[v, fo+i] * cgY[o*dI+i]   (lane = v)
        {
            const float* fv = &s_Fv[(eloc*16 + l) * 9 + fo];
            for (int o = 0; o < dO; ++o) {
                float t = 0.f;
                const float* cy = &s_cgy[eloc][o*dI];
                for (int i = 0; i < dI; ++i) t += fv[i] * cy[i];
                s_tmp[eloc*84 + o*16 + l] = t;
            }
        }
        __syncthreads();

        // stage 3: msg[ob+o][w] += sum_v W[w,v] * tmp[v,o]   (lane = w)
        {
            const float* Wrow = &s_W[eloc*WST + 16*l];
            const float4 w0 = *reinterpret_cast<const float4*>(Wrow);
            const float4 w1 = *reinterpret_cast<const float4*>(Wrow + 4);
            const float4 w2 = *reinterpret_cast<const float4*>(Wrow + 8);
            const float4 w3 = *reinterpret_cast<const float4*>(Wrow + 12);
            for (int o = 0; o < dO; ++o) {
                const float4* tq = reinterpret_cast<const float4*>(&s_tmp[eloc*84 + o*16]);
                const float4 t0 = tq[0], t1 = tq[1], t2 = tq[2], t3 = tq[3];
                float s = w0.x*t0.x + w0.y*t0.y + w0.z*t0.z + w0.w*t0.w
                        + w1.x*t1.x + w1.y*t1.y + w1.z*t1.z + w1.w*t1.w
                        + w2.x*t2.x + w2.y*t2.y + w2.z*t2.z + w2.w*t2.w
                        + w3.x*t3.x + w3.y*t3.y + w3.z*t3.z + w3.w*t3.w;
                const int idx = eloc*144 + (ob + o)*16 + l;
                s_msg[idx] += s;          // lane-private column: no cross-lane race
            }
        }
        __syncthreads();   // WAR: next path rewrites s_W/s_cgy/s_tmp
    }

    // tail: coalesced plain stores
    if (act) {
        float* m = msg + (size_t)e * 144 + l;
        #pragma unroll
        for (int j = 0; j < 9; ++j) m[j * 16] = s_msg[eloc*144 + j*16 + l];
    }
}

// ---------------- Phase B: node gather-reduce (no atomics) ----------------
__global__ __launch_bounds__(BLK)
void se3_gather(const float* __restrict__ msg, const int* __restrict__ off,
                const int* __restrict__ eidx, const float* __restrict__ Nn,
                float* __restrict__ Out, const int nN)
{
    const int l = threadIdx.x & 15;
    const int g = threadIdx.x >> 4;
    const int n = blockIdx.x * 16 + g;
    if (n >= nN) return;

    const int i0 = off[n], i1 = off[n + 1];
    float s[9];
    #pragma unroll
    for (int j = 0; j < 9; ++j) s[j] = 0.f;

    for (int idx = i0; idx < i1; ++idx) {
        const int eid = eidx[idx];
        const float* m = msg + (size_t)eid * 144 + l;
        #pragma unroll
        for (int j = 0; j < 9; ++j) s[j] += m[j * 16];
    }

    const float nn = Nn[n];
    float* orow = Out + (size_t)n * 144;
    orow[l] = s[0] * nn;
    #pragma unroll
    for (int o = 0; o < 3; ++o) orow[16 + l*3 + o] = s[1+o] * nn;
    #pragma unroll
    for (int o = 0; o < 5; ++o) orow[64 + l*5 + o] = s[4+o] * nn;
}

// ---------------- CSR build (by destination) ----------------
__global__ void k_count(const int* __restrict__ Ma, int* __restrict__ cur, int E) {
    int e = blockIdx.x * blockDim.x + threadIdx.x;
    if (e < E) atomicAdd(&cur[Ma[e]], 1);
}

__global__ void k_scan(int* __restrict__ cur, int* __restrict__ off, int N) {
    __shared__ int part[BLK];
    const int t = threadIdx.x;
    const int K = (N + BLK - 1) / BLK;
    const int i0 = t * K, i1 = min(i0 + K, N);
    int s = 0;
    for (int i = i0; i < i1; ++i) s += cur[i];
    part[t] = s;
    __syncthreads();
    if (t == 0) {
        int a = 0;
        for (int j = 0; j < BLK; ++j) { int v = part[j]; part[j] = a; a += v; }
        off[N] = a;
    }
    __syncthreads();
    int a = part[t];
    for (int i = i0; i < i1; ++i) {
        int v = cur[i];
        off[i] = a;
        cur[i] = a;       // reuse as scatter cursor
        a += v;
    }
}

__global__ void k_scatter(const int* __restrict__ Ma, int* __restrict__ cur,
                          int* __restrict__ eidx, int E) {
    int e = blockIdx.x * blockDim.x + threadIdx.x;
    if (e < E) {
        int pos = atomicAdd(&cur[Ma[e]], 1);
        eidx[pos] = e;
    }
}

extern "C" void kernel_launch(void* const* d_in, const int* in_sizes, int n_in,
                              void* d_out, int out_size, void* d_ws, size_t ws_size,
                              hipStream_t stream) {
    const float* F   = (const float*)d_in[0];
    const float* R   = (const float*)d_in[1];
    const float* Ys  = (const float*)d_in[2];
    const float* Rad = (const float*)d_in[3];
    const float* cg  = (const float*)d_in[4];
    const float* Nn  = (const float*)d_in[5];
    const int*   Ma  = (const int*)d_in[6];
    const int*   Mb  = (const int*)d_in[7];
    float* Out = (float*)d_out;

    const int nE = in_sizes[6];   // edges
    const int nN = in_sizes[5];   // nodes

    // ws layout: [cur nN][off nN+1][eidx nE][pad][msg nE*144 floats]
    int* wsI  = (int*)d_ws;
    int* cur  = wsI;
    int* off  = wsI + nN;
    int* eidx = wsI + 2*nN + 1;
    size_t msgOff = ((size_t)(2*nN + 1 + nE) + 63) & ~(size_t)63;
    float* msg = (float*)d_ws + msgOff;

    hipMemsetAsync(cur, 0, (size_t)nN * sizeof(int), stream);
    k_count  <<<(nE + BLK - 1) / BLK, BLK, 0, stream>>>(Ma, cur, nE);
    k_scan   <<<1, BLK, 0, stream>>>(cur, off, nN);
    k_scatter<<<(nE + BLK - 1) / BLK, BLK, 0, stream>>>(Ma, cur, eidx, nE);

    se3_msg   <<<(nE + EPB - 1) / EPB, BLK, 0, stream>>>(F, R, Ys, Rad, cg, Mb, msg, nE);
    se3_gather<<<(nN + 15) / 16, BLK, 0, stream>>>(msg, off, eidx, Nn, Out, nN);
}